// Round 2
// baseline (389.204 us; speedup 1.0000x reference)
//
#include <hip/hip_runtime.h>
#include <cstdint>

#define D 256
#define NC 32
#define NCLS 10
#define KNN 10
#define NBLK 32
#define SPLIT 8

__device__ __forceinline__ float wave_sum(float v) {
  #pragma unroll
  for (int off = 32; off; off >>= 1) v += __shfl_xor(v, off);
  return v;
}

// ---------------- fused gram + Gauss-Jordan solve + scalar stats ----------------
// 1 block x 1024 threads. Phase 1: aug[32][42] = [C^T C | C^T W] via one dot per thread.
// Phase 2: lanes 0-31 of wave 0 hold one row each in registers; shfl-broadcast GJ.
#define AUGW (NC + NCLS)   // 42
__global__ __launch_bounds__(1024) void k_gramsolve(const float* __restrict__ C,
                                                    const float* __restrict__ W,
                                                    float* __restrict__ S,
                                                    float* __restrict__ out, int bs) {
  __shared__ float aug[NC * AUGW];
  int tid = threadIdx.x;
  for (int e = tid; e < NC * AUGW; e += 1024) {
    int i = e / AUGW, jj = e % AUGW;
    float acc = 0.f;
    if (jj < NC) {
      for (int d = 0; d < D; ++d) acc += C[d * NC + i] * C[d * NC + jj];
    } else {
      int cls = jj - NC;
      for (int d = 0; d < D; ++d) acc += C[d * NC + i] * W[d * NCLS + cls];
    }
    aug[e] = acc;
  }
  __syncthreads();

  if (tid < NC) {
    int lane = tid;              // lane == row i
    float row[AUGW];
    #pragma unroll
    for (int c = 0; c < AUGW; ++c) row[c] = aug[lane * AUGW + c];

    // stats on gram
    float rsum = 0.f;
    #pragma unroll
    for (int c = 0; c < NC; ++c) rsum += row[c];
    float diag = row[lane];
    #pragma unroll
    for (int off = 16; off; off >>= 1) {
      rsum += __shfl_xor(rsum, off);
      diag += __shfl_xor(diag, off);
    }
    if (lane == 0) {
      out[(size_t)2 * bs * NCLS + 1] = (rsum - diag) / (float)(NC * NC); // L_sparse_2
      out[(size_t)2 * bs * NCLS + 2] = diag / (float)(NC * NC);          // norm_metrics
    }

    // Gauss-Jordan, no pivoting (gram diagonally dominant)
    for (int k = 0; k < NC; ++k) {
      float prow[AUGW];
      #pragma unroll
      for (int c = 0; c < AUGW; ++c) prow[c] = __shfl(row[c], k);
      float pinv = 1.0f / prow[k];
      float f = row[k] * pinv;
      if (lane == k) {
        #pragma unroll
        for (int c = 0; c < AUGW; ++c) row[c] *= pinv;
      } else {
        #pragma unroll
        for (int c = 0; c < AUGW; ++c) row[c] -= f * prow[c];
      }
    }
    #pragma unroll
    for (int c = 0; c < NCLS; ++c) S[lane * NCLS + c] = row[NC + c];
  }
}

// ---------------- predictions: orig_pred and y_pred ----------------
__global__ __launch_bounds__(256) void k_pred(const float* __restrict__ X,
                                              const float* __restrict__ C,
                                              const float* __restrict__ W,
                                              const float* __restrict__ bvec,
                                              const float* __restrict__ S,
                                              float* __restrict__ out, int bs) {
  int t = blockIdx.x * 256 + threadIdx.x;
  int r = t / SPLIT, q = t % SPLIT;
  if (r >= bs) return;
  const float* x = X + (size_t)r * D;
  float a[NC], o[NCLS];
  #pragma unroll
  for (int c = 0; c < NC; ++c) a[c] = 0.f;
  #pragma unroll
  for (int c = 0; c < NCLS; ++c) o[c] = 0.f;

  int d0 = q * (D / SPLIT);
  for (int d = d0; d < d0 + D / SPLIT; d += 4) {
    float4 xv = *reinterpret_cast<const float4*>(x + d);
    #pragma unroll
    for (int dd = 0; dd < 4; ++dd) {
      float xd = (dd == 0) ? xv.x : (dd == 1) ? xv.y : (dd == 2) ? xv.z : xv.w;
      #pragma unroll
      for (int c = 0; c < NC; ++c) a[c] += xd * C[(d + dd) * NC + c];
      #pragma unroll
      for (int c = 0; c < NCLS; ++c) o[c] += xd * W[(d + dd) * NCLS + c];
    }
  }
  #pragma unroll
  for (int off = 1; off < SPLIT; off <<= 1) {
    #pragma unroll
    for (int c = 0; c < NC; ++c) a[c] += __shfl_xor(a[c], off);
    #pragma unroll
    for (int c = 0; c < NCLS; ++c) o[c] += __shfl_xor(o[c], off);
  }
  if (q == 0) {
    #pragma unroll
    for (int cls = 0; cls < NCLS; ++cls) {
      float y = bvec[cls];
      #pragma unroll
      for (int c = 0; c < NC; ++c) y += a[c] * S[c * NCLS + cls];
      out[(size_t)r * NCLS + cls] = o[cls] + bvec[cls];
      out[(size_t)bs * NCLS + (size_t)r * NCLS + cls] = y;
    }
  }
}

// ---------------- key = x2 - 2*xc, LDS-tiled ----------------
// 64 rows/block, 2 chunks of 128 cols. LDS layout: float4 tile[row][col4 ^ (row&31)]
// (16B-aligned, minimal bank pattern for both coalesced staging writes and
//  row-per-lane ds_read_b128). wave == concept group -> concept loads wave-uniform.
__global__ __launch_bounds__(256) void k_key(const float* __restrict__ X,
                                             const float* __restrict__ Cc,
                                             float* __restrict__ keyT, int N) {
  __shared__ float4 tile[64 * 32];   // 32 KB
  const float4* Xv = reinterpret_cast<const float4*>(X);
  int t = threadIdx.x;
  int rowbase = blockIdx.x * 64;
  int r = t & 63;        // row within tile
  int g = t >> 6;        // concept group (wave id): concepts g*8 .. g*8+7
  int rb = r & 31;

  float acc[8];
  #pragma unroll
  for (int k = 0; k < 8; ++k) acc[k] = 0.f;
  float x2 = 0.f;

  for (int chunk = 0; chunk < 2; ++chunk) {
    __syncthreads();   // previous chunk's readers done before overwrite
    #pragma unroll
    for (int i = 0; i < 8; ++i) {
      int e = i * 256 + t;
      int row = e >> 5, col4 = e & 31;
      int gr = rowbase + row; if (gr >= N) gr = N - 1;
      float4 v = Xv[(size_t)gr * (D / 4) + chunk * 32 + col4];
      tile[row * 32 + (col4 ^ (row & 31))] = v;
    }
    __syncthreads();

    const float* cbase = Cc + (size_t)(chunk * 128) * NC + g * 8;
    #pragma unroll 4
    for (int d4 = 0; d4 < 32; ++d4) {
      float4 x = tile[r * 32 + (d4 ^ rb)];
      const float* crow = cbase + (size_t)d4 * 4 * NC;
      #pragma unroll
      for (int k = 0; k < 8; ++k) {
        acc[k] += x.x * crow[k] + x.y * crow[NC + k] + x.z * crow[2 * NC + k] + x.w * crow[3 * NC + k];
      }
      x2 += x.x * x.x + x.y * x.y + x.z * x.z + x.w * x.w;
    }
  }

  int gr = rowbase + r;
  if (gr < N) {
    #pragma unroll
    for (int k = 0; k < 8; ++k) {
      keyT[(size_t)(g * 8 + k) * N + gr] = x2 - 2.f * acc[k];
    }
  }
}

// ---------------- per-(concept, chunk) exact top-10 ----------------
__global__ __launch_bounds__(256) void k_topk(const float* __restrict__ keyT,
                                              float* __restrict__ candK,
                                              int* __restrict__ candI, int N) {
  int j = blockIdx.y, blk = blockIdx.x, tid = threadIdx.x;
  const float* key = keyT + (size_t)j * N;
  int per = (N + NBLK - 1) / NBLK;
  int lo = blk * per;
  int hi = lo + per; if (hi > N) hi = N;

  float bk[KNN]; int bi[KNN];
  #pragma unroll
  for (int q = 0; q < KNN; ++q) { bk[q] = 3.4e38f; bi[q] = 0x7fffffff; }

  for (int i = lo + tid; i < hi; i += 256) {
    float v = key[i];
    if (v < bk[KNN - 1] || (v == bk[KNN - 1] && i < bi[KNN - 1])) {
      float cv = v; int ci = i;
      #pragma unroll
      for (int q = 0; q < KNN; ++q) {
        bool take = (cv < bk[q]) || (cv == bk[q] && ci < bi[q]);
        if (take) {
          float tf = bk[q]; bk[q] = cv; cv = tf;
          int ti = bi[q]; bi[q] = ci; ci = ti;
        }
      }
    }
  }

  __shared__ float sk[256 * KNN];
  __shared__ int si[256 * KNN];
  __shared__ float wv_[4]; __shared__ int wi_[4];
  #pragma unroll
  for (int q = 0; q < KNN; ++q) { sk[tid * KNN + q] = bk[q]; si[tid * KNN + q] = bi[q]; }
  __syncthreads();

  int p = 0;
  int lane = tid & 63, wv = tid >> 6;
  for (int rr = 0; rr < KNN; ++rr) {
    float myv = (p < KNN) ? sk[tid * KNN + p] : 3.4e38f;
    int mygi = (p < KNN) ? si[tid * KNN + p] : 0x7fffffff;
    float hv = myv; int hgi = mygi;
    #pragma unroll
    for (int off = 32; off; off >>= 1) {
      float ov = __shfl_xor(hv, off); int oi = __shfl_xor(hgi, off);
      if (ov < hv || (ov == hv && oi < hgi)) { hv = ov; hgi = oi; }
    }
    if (lane == 0) { wv_[wv] = hv; wi_[wv] = hgi; }
    __syncthreads();
    float bv = wv_[0]; int bgi = wi_[0];
    #pragma unroll
    for (int w = 1; w < 4; ++w) {
      if (wv_[w] < bv || (wv_[w] == bv && wi_[w] < bgi)) { bv = wv_[w]; bgi = wi_[w]; }
    }
    if (p < KNN && myv == bv && mygi == bgi) p++;
    if (tid == 0) {
      candK[((size_t)j * NBLK + blk) * KNN + rr] = bv;
      candI[((size_t)j * NBLK + blk) * KNN + rr] = bgi;
    }
    __syncthreads();
  }
}

// ---------------- merge candidates, gather knn, dot with concept ----------------
__global__ __launch_bounds__(256) void k_final(const float* __restrict__ candK,
                                               const int* __restrict__ candI,
                                               const float* __restrict__ X,
                                               const float* __restrict__ Cc,
                                               float* __restrict__ dots) {
  int j = blockIdx.x, tid = threadIdx.x;
  const int M = NBLK * KNN; // 320
  __shared__ float mk[M]; __shared__ int mi[M];
  __shared__ int topIdx[KNN];
  __shared__ float wvv[4]; __shared__ int wvi[4]; __shared__ int wvp[4];
  __shared__ float rsum[4];
  for (int e = tid; e < M; e += 256) { mk[e] = candK[(size_t)j * M + e]; mi[e] = candI[(size_t)j * M + e]; }
  __syncthreads();

  int lane = tid & 63, wv = tid >> 6;
  for (int rr = 0; rr < KNN; ++rr) {
    float v = 3.4e38f; int gi = 0x7fffffff; int pos = -1;
    for (int e = tid; e < M; e += 256) {
      if (mk[e] < v || (mk[e] == v && mi[e] < gi)) { v = mk[e]; gi = mi[e]; pos = e; }
    }
    #pragma unroll
    for (int off = 32; off; off >>= 1) {
      float ov = __shfl_xor(v, off); int ogi = __shfl_xor(gi, off); int op = __shfl_xor(pos, off);
      if (ov < v || (ov == v && ogi < gi)) { v = ov; gi = ogi; pos = op; }
    }
    if (lane == 0) { wvv[wv] = v; wvi[wv] = gi; wvp[wv] = pos; }
    __syncthreads();
    float bv = wvv[0]; int bgi = wvi[0]; int bpos = wvp[0];
    #pragma unroll
    for (int w = 1; w < 4; ++w) {
      if (wvv[w] < bv || (wvv[w] == bv && wvi[w] < bgi)) { bv = wvv[w]; bgi = wvi[w]; bpos = wvp[w]; }
    }
    if (tid == 0) { topIdx[rr] = bgi; mk[bpos] = 3.4e38f; }
    __syncthreads();
  }

  float cj = Cc[tid * NC + j];
  float acc = 0.f;
  #pragma unroll
  for (int k = 0; k < KNN; ++k) acc += X[(size_t)topIdx[k] * D + tid] * cj;
  acc = wave_sum(acc);
  if (lane == 0) rsum[wv] = acc;
  __syncthreads();
  if (tid == 0) dots[j] = (rsum[0] + rsum[1] + rsum[2] + rsum[3]) * (1.0f / KNN);
}

__global__ __launch_bounds__(64) void k_scal(const float* __restrict__ dots,
                                             float* __restrict__ out, int bs) {
  int lane = threadIdx.x;
  float v = (lane < NC) ? dots[lane] : 0.f;
  v = wave_sum(v);
  if (lane == 0) out[(size_t)2 * bs * NCLS] = v / (float)NC;
}

extern "C" void kernel_launch(void* const* d_in, const int* in_sizes, int n_in,
                              void* d_out, int out_size, void* d_ws, size_t ws_size,
                              hipStream_t stream) {
  const float* Xb = (const float*)d_in[0]; // train_embedding [bs][D]
  const float* XN = (const float*)d_in[1]; // train_embeddings [N][D]
  const float* C  = (const float*)d_in[2]; // concept [D][NC]
  const float* W  = (const float*)d_in[3]; // W_hx [D][NCLS]
  const float* bv = (const float*)d_in[4]; // b_hx [NCLS]
  float* out = (float*)d_out;

  int bs = in_sizes[0] / D;   // 4096
  int N  = in_sizes[1] / D;   // 200000

  float* w = (float*)d_ws;
  size_t offKey  = 0;
  size_t offS    = (size_t)NC * N;
  size_t offCK   = offS + NC * NCLS;
  size_t offCI   = offCK + (size_t)NC * NBLK * KNN;
  size_t offDots = offCI + (size_t)NC * NBLK * KNN;

  float* keyT  = w + offKey;
  float* S     = w + offS;
  float* candK = w + offCK;
  int*   candI = (int*)(w + offCI);
  float* dots  = w + offDots;

  k_key<<<dim3((N + 63) / 64), dim3(256), 0, stream>>>(XN, C, keyT, N);
  k_gramsolve<<<dim3(1), dim3(1024), 0, stream>>>(C, W, S, out, bs);
  k_pred<<<dim3(bs * SPLIT / 256), dim3(256), 0, stream>>>(Xb, C, W, bv, S, out, bs);
  k_topk<<<dim3(NBLK, NC), dim3(256), 0, stream>>>(keyT, candK, candI, N);
  k_final<<<dim3(NC), dim3(256), 0, stream>>>(candK, candI, XN, C, dots);
  k_scal<<<dim3(1), dim3(64), 0, stream>>>(dots, out, bs);
}

// Round 3
// 266.416 us; speedup vs baseline: 1.4609x; 1.4609x over previous
//
#include <hip/hip_runtime.h>
#include <cstdint>

#define D 256
#define NC 32
#define NCLS 10
#define KNN 10
#define NBLK 32
#define SPLIT 8
#define KROWS 256   // rows per k_key block
#define KCH 8       // d-chunks of 32

typedef const __attribute__((address_space(1))) unsigned int* gp1_t;
typedef __attribute__((address_space(3))) unsigned int* sp3_t;

__device__ __forceinline__ float wave_sum(float v) {
  #pragma unroll
  for (int off = 32; off; off >>= 1) v += __shfl_xor(v, off);
  return v;
}

// ---------------- key = x2 - 2*xc : register-tiled, LDS double-buffered ----------------
// block = 256 rows x 32 concepts. wave g -> concepts g*8..g*8+7 (uniform c addresses).
// lane owns rows {lane, lane+64, lane+128, lane+192}; acc tile 4x8 per lane.
// X staged global->LDS via global_load_lds(16B), source pre-swizzled (d4 ^ row&7).
__global__ __launch_bounds__(256) void k_key(const float* __restrict__ X,
                                             const float* __restrict__ Cc,
                                             float* __restrict__ keyT, int N) {
  __shared__ float4 xt[2][KROWS * 8];   // 2 x 32 KB
  int t = threadIdx.x;
  int lane = t & 63, wv = t >> 6;
  int rowbase = blockIdx.x * KROWS;

  // ---- stage chunk 0 into buf 0 ----
  #pragma unroll
  for (int j = 0; j < 8; ++j) {
    int e = (wv * 8 + j) * 64 + lane;       // float4 slot in LDS (linear)
    int row = e >> 3, s = e & 7;
    int d4 = s ^ (row & 7);                 // pre-swizzled global source
    int gr = rowbase + row; if (gr >= N) gr = N - 1;
    const float* src = X + (size_t)gr * D + d4 * 4;
    __builtin_amdgcn_global_load_lds((gp1_t)(const void*)src,
                                     (sp3_t)(void*)&xt[0][(wv * 8 + j) * 64], 16, 0, 0);
  }

  float acc[4][8];
  float x2[4];
  #pragma unroll
  for (int i = 0; i < 4; ++i) {
    x2[i] = 0.f;
    #pragma unroll
    for (int k = 0; k < 8; ++k) acc[i][k] = 0.f;
  }

  for (int ch = 0; ch < KCH; ++ch) {
    __syncthreads();                        // drains vmcnt: chunk ch staged & visible
    int cb = ch & 1, nb = cb ^ 1;
    if (ch + 1 < KCH) {                     // prefetch chunk ch+1 during compute of ch
      #pragma unroll
      for (int j = 0; j < 8; ++j) {
        int e = (wv * 8 + j) * 64 + lane;
        int row = e >> 3, s = e & 7;
        int d4 = s ^ (row & 7);
        int gr = rowbase + row; if (gr >= N) gr = N - 1;
        const float* src = X + (size_t)gr * D + (ch + 1) * 32 + d4 * 4;
        __builtin_amdgcn_global_load_lds((gp1_t)(const void*)src,
                                         (sp3_t)(void*)&xt[nb][(wv * 8 + j) * 64], 16, 0, 0);
      }
    }
    // ---- compute chunk ch ----
    #pragma unroll
    for (int d4 = 0; d4 < 8; ++d4) {
      int sl = d4 ^ (lane & 7);             // swizzle slot (same for all 4 rows of this lane)
      float4 xv[4];
      #pragma unroll
      for (int i = 0; i < 4; ++i) xv[i] = xt[cb][(lane + i * 64) * 8 + sl];
      #pragma unroll
      for (int dd = 0; dd < 4; ++dd) {
        const float* cp = Cc + (size_t)(ch * 32 + d4 * 4 + dd) * NC + wv * 8;
        float4 ca = *reinterpret_cast<const float4*>(cp);
        float4 cb4 = *reinterpret_cast<const float4*>(cp + 4);
        #pragma unroll
        for (int i = 0; i < 4; ++i) {
          float xd = reinterpret_cast<const float*>(&xv[i])[dd];
          acc[i][0] += xd * ca.x;  acc[i][1] += xd * ca.y;
          acc[i][2] += xd * ca.z;  acc[i][3] += xd * ca.w;
          acc[i][4] += xd * cb4.x; acc[i][5] += xd * cb4.y;
          acc[i][6] += xd * cb4.z; acc[i][7] += xd * cb4.w;
          x2[i] += xd * xd;
        }
      }
    }
  }

  #pragma unroll
  for (int i = 0; i < 4; ++i) {
    int gr = rowbase + lane + i * 64;
    if (gr < N) {
      #pragma unroll
      for (int k = 0; k < 8; ++k)
        keyT[(size_t)(wv * 8 + k) * N + gr] = x2[i] - 2.f * acc[i][k];
    }
  }
}

// ---------------- fused gram + Gauss-Jordan solve + scalar stats ----------------
#define AUGW (NC + NCLS)   // 42
__global__ __launch_bounds__(1024) void k_gramsolve(const float* __restrict__ C,
                                                    const float* __restrict__ W,
                                                    float* __restrict__ S,
                                                    float* __restrict__ out, int bs) {
  __shared__ float Cs[D * NC];     // 32 KB
  __shared__ float Ws[D * NCLS];   // 10 KB
  __shared__ float aug[NC * AUGW];
  int tid = threadIdx.x;
  { // coalesced stage
    const float4* C4 = (const float4*)C;  float4* Cs4 = (float4*)Cs;
    Cs4[tid] = C4[tid]; Cs4[tid + 1024] = C4[tid + 1024];
    const float4* W4 = (const float4*)W;  float4* Ws4 = (float4*)Ws;
    if (tid < (D * NCLS) / 4) Ws4[tid] = W4[tid];
  }
  __syncthreads();
  for (int e = tid; e < NC * AUGW; e += 1024) {
    int i = e / AUGW, jj = e % AUGW;
    float acc = 0.f;
    if (jj < NC) {
      for (int d = 0; d < D; ++d) acc += Cs[d * NC + i] * Cs[d * NC + jj];
    } else {
      int cls = jj - NC;
      for (int d = 0; d < D; ++d) acc += Cs[d * NC + i] * Ws[d * NCLS + cls];
    }
    aug[e] = acc;
  }
  __syncthreads();

  if (tid < NC) {
    int lane = tid;              // lane == row i
    float row[AUGW];
    #pragma unroll
    for (int c = 0; c < AUGW; ++c) row[c] = aug[lane * AUGW + c];

    float rsum = 0.f;
    #pragma unroll
    for (int c = 0; c < NC; ++c) rsum += row[c];
    float diag = row[lane];
    #pragma unroll
    for (int off = 16; off; off >>= 1) {
      rsum += __shfl_xor(rsum, off);
      diag += __shfl_xor(diag, off);
    }
    if (lane == 0) {
      out[(size_t)2 * bs * NCLS + 1] = (rsum - diag) / (float)(NC * NC); // L_sparse_2
      out[(size_t)2 * bs * NCLS + 2] = diag / (float)(NC * NC);          // norm_metrics
    }

    // Gauss-Jordan, no pivoting (gram diagonally dominant)
    for (int k = 0; k < NC; ++k) {
      float prow[AUGW];
      #pragma unroll
      for (int c = 0; c < AUGW; ++c) prow[c] = __shfl(row[c], k);
      float pinv = 1.0f / prow[k];
      float f = row[k] * pinv;
      if (lane == k) {
        #pragma unroll
        for (int c = 0; c < AUGW; ++c) row[c] *= pinv;
      } else {
        #pragma unroll
        for (int c = 0; c < AUGW; ++c) row[c] -= f * prow[c];
      }
    }
    #pragma unroll
    for (int c = 0; c < NCLS; ++c) S[lane * NCLS + c] = row[NC + c];
  }
}

// ---------------- predictions: orig_pred and y_pred ----------------
__global__ __launch_bounds__(256) void k_pred(const float* __restrict__ X,
                                              const float* __restrict__ C,
                                              const float* __restrict__ W,
                                              const float* __restrict__ bvec,
                                              const float* __restrict__ S,
                                              float* __restrict__ out, int bs) {
  int t = blockIdx.x * 256 + threadIdx.x;
  int r = t / SPLIT, q = t % SPLIT;
  if (r >= bs) return;
  const float* x = X + (size_t)r * D;
  float a[NC], o[NCLS];
  #pragma unroll
  for (int c = 0; c < NC; ++c) a[c] = 0.f;
  #pragma unroll
  for (int c = 0; c < NCLS; ++c) o[c] = 0.f;

  int d0 = q * (D / SPLIT);
  for (int d = d0; d < d0 + D / SPLIT; d += 4) {
    float4 xv = *reinterpret_cast<const float4*>(x + d);
    #pragma unroll
    for (int dd = 0; dd < 4; ++dd) {
      float xd = reinterpret_cast<const float*>(&xv)[dd];
      #pragma unroll
      for (int c = 0; c < NC; ++c) a[c] += xd * C[(d + dd) * NC + c];
      #pragma unroll
      for (int c = 0; c < NCLS; ++c) o[c] += xd * W[(d + dd) * NCLS + c];
    }
  }
  #pragma unroll
  for (int off = 1; off < SPLIT; off <<= 1) {
    #pragma unroll
    for (int c = 0; c < NC; ++c) a[c] += __shfl_xor(a[c], off);
    #pragma unroll
    for (int c = 0; c < NCLS; ++c) o[c] += __shfl_xor(o[c], off);
  }
  if (q == 0) {
    #pragma unroll
    for (int cls = 0; cls < NCLS; ++cls) {
      float y = bvec[cls];
      #pragma unroll
      for (int c = 0; c < NC; ++c) y += a[c] * S[c * NCLS + cls];
      out[(size_t)r * NCLS + cls] = o[cls] + bvec[cls];
      out[(size_t)bs * NCLS + (size_t)r * NCLS + cls] = y;
    }
  }
}

// ---------------- per-(concept, chunk) exact top-10, float4 scan ----------------
__global__ __launch_bounds__(256) void k_topk(const float* __restrict__ keyT,
                                              float* __restrict__ candK,
                                              int* __restrict__ candI, int N) {
  int j = blockIdx.y, blk = blockIdx.x, tid = threadIdx.x;
  const float* key = keyT + (size_t)j * N;
  int per = (((N + NBLK - 1) / NBLK) + 3) & ~3;   // multiple of 4
  int lo = blk * per;
  int hi = lo + per; if (hi > N) hi = N;

  float bk[KNN]; int bi[KNN];
  #pragma unroll
  for (int q = 0; q < KNN; ++q) { bk[q] = 3.4e38f; bi[q] = 0x7fffffff; }

  if (lo < N) {
    const float4* key4 = reinterpret_cast<const float4*>(key + lo);
    int n4 = (hi - lo) >> 2;
    for (int i4 = tid; i4 < n4; i4 += 256) {
      float4 v4 = key4[i4];
      #pragma unroll
      for (int c = 0; c < 4; ++c) {
        float v = reinterpret_cast<const float*>(&v4)[c];
        int gi = lo + (i4 << 2) + c;
        if (v < bk[KNN - 1] || (v == bk[KNN - 1] && gi < bi[KNN - 1])) {
          float cv = v; int ci = gi;
          #pragma unroll
          for (int q = 0; q < KNN; ++q) {
            bool take = (cv < bk[q]) || (cv == bk[q] && ci < bi[q]);
            if (take) {
              float tf = bk[q]; bk[q] = cv; cv = tf;
              int ti = bi[q]; bi[q] = ci; ci = ti;
            }
          }
        }
      }
    }
    // tail (none when N%4==0, kept for safety)
    for (int i = lo + (n4 << 2) + tid; i < hi; i += 256) {
      float v = key[i];
      if (v < bk[KNN - 1] || (v == bk[KNN - 1] && i < bi[KNN - 1])) {
        float cv = v; int ci = i;
        #pragma unroll
        for (int q = 0; q < KNN; ++q) {
          bool take = (cv < bk[q]) || (cv == bk[q] && ci < bi[q]);
          if (take) {
            float tf = bk[q]; bk[q] = cv; cv = tf;
            int ti = bi[q]; bi[q] = ci; ci = ti;
          }
        }
      }
    }
  }

  __shared__ float sk[256 * KNN];
  __shared__ int si[256 * KNN];
  __shared__ float wv_[4]; __shared__ int wi_[4];
  #pragma unroll
  for (int q = 0; q < KNN; ++q) { sk[tid * KNN + q] = bk[q]; si[tid * KNN + q] = bi[q]; }
  __syncthreads();

  int p = 0;
  int lane = tid & 63, wv = tid >> 6;
  for (int rr = 0; rr < KNN; ++rr) {
    float myv = (p < KNN) ? sk[tid * KNN + p] : 3.4e38f;
    int mygi = (p < KNN) ? si[tid * KNN + p] : 0x7fffffff;
    float hv = myv; int hgi = mygi;
    #pragma unroll
    for (int off = 32; off; off >>= 1) {
      float ov = __shfl_xor(hv, off); int oi = __shfl_xor(hgi, off);
      if (ov < hv || (ov == hv && oi < hgi)) { hv = ov; hgi = oi; }
    }
    if (lane == 0) { wv_[wv] = hv; wi_[wv] = hgi; }
    __syncthreads();
    float bv = wv_[0]; int bgi = wi_[0];
    #pragma unroll
    for (int w = 1; w < 4; ++w) {
      if (wv_[w] < bv || (wv_[w] == bv && wi_[w] < bgi)) { bv = wv_[w]; bgi = wi_[w]; }
    }
    if (p < KNN && myv == bv && mygi == bgi) p++;
    if (tid == 0) {
      candK[((size_t)j * NBLK + blk) * KNN + rr] = bv;
      candI[((size_t)j * NBLK + blk) * KNN + rr] = bgi;
    }
    __syncthreads();
  }
}

// ---------------- merge candidates, gather knn, dot with concept ----------------
__global__ __launch_bounds__(256) void k_final(const float* __restrict__ candK,
                                               const int* __restrict__ candI,
                                               const float* __restrict__ X,
                                               const float* __restrict__ Cc,
                                               float* __restrict__ dots) {
  int j = blockIdx.x, tid = threadIdx.x;
  const int M = NBLK * KNN; // 320
  __shared__ float mk[M]; __shared__ int mi[M];
  __shared__ int topIdx[KNN];
  __shared__ float wvv[4]; __shared__ int wvi[4]; __shared__ int wvp[4];
  __shared__ float rsum[4];
  for (int e = tid; e < M; e += 256) { mk[e] = candK[(size_t)j * M + e]; mi[e] = candI[(size_t)j * M + e]; }
  __syncthreads();

  int lane = tid & 63, wv = tid >> 6;
  for (int rr = 0; rr < KNN; ++rr) {
    float v = 3.4e38f; int gi = 0x7fffffff; int pos = -1;
    for (int e = tid; e < M; e += 256) {
      if (mk[e] < v || (mk[e] == v && mi[e] < gi)) { v = mk[e]; gi = mi[e]; pos = e; }
    }
    #pragma unroll
    for (int off = 32; off; off >>= 1) {
      float ov = __shfl_xor(v, off); int ogi = __shfl_xor(gi, off); int op = __shfl_xor(pos, off);
      if (ov < v || (ov == v && ogi < gi)) { v = ov; gi = ogi; pos = op; }
    }
    if (lane == 0) { wvv[wv] = v; wvi[wv] = gi; wvp[wv] = pos; }
    __syncthreads();
    float bv = wvv[0]; int bgi = wvi[0]; int bpos = wvp[0];
    #pragma unroll
    for (int w = 1; w < 4; ++w) {
      if (wvv[w] < bv || (wvv[w] == bv && wvi[w] < bgi)) { bv = wvv[w]; bgi = wvi[w]; bpos = wvp[w]; }
    }
    if (tid == 0) { topIdx[rr] = bgi; mk[bpos] = 3.4e38f; }
    __syncthreads();
  }

  float cj = Cc[tid * NC + j];
  float acc = 0.f;
  #pragma unroll
  for (int k = 0; k < KNN; ++k) acc += X[(size_t)topIdx[k] * D + tid] * cj;
  acc = wave_sum(acc);
  if (lane == 0) rsum[wv] = acc;
  __syncthreads();
  if (tid == 0) dots[j] = (rsum[0] + rsum[1] + rsum[2] + rsum[3]) * (1.0f / KNN);
}

__global__ __launch_bounds__(64) void k_scal(const float* __restrict__ dots,
                                             float* __restrict__ out, int bs) {
  int lane = threadIdx.x;
  float v = (lane < NC) ? dots[lane] : 0.f;
  v = wave_sum(v);
  if (lane == 0) out[(size_t)2 * bs * NCLS] = v / (float)NC;
}

extern "C" void kernel_launch(void* const* d_in, const int* in_sizes, int n_in,
                              void* d_out, int out_size, void* d_ws, size_t ws_size,
                              hipStream_t stream) {
  const float* Xb = (const float*)d_in[0]; // train_embedding [bs][D]
  const float* XN = (const float*)d_in[1]; // train_embeddings [N][D]
  const float* C  = (const float*)d_in[2]; // concept [D][NC]
  const float* W  = (const float*)d_in[3]; // W_hx [D][NCLS]
  const float* bv = (const float*)d_in[4]; // b_hx [NCLS]
  float* out = (float*)d_out;

  int bs = in_sizes[0] / D;   // 4096
  int N  = in_sizes[1] / D;   // 200000

  float* w = (float*)d_ws;
  size_t offKey  = 0;
  size_t offS    = (size_t)NC * N;
  size_t offCK   = offS + NC * NCLS;
  size_t offCI   = offCK + (size_t)NC * NBLK * KNN;
  size_t offDots = offCI + (size_t)NC * NBLK * KNN;

  float* keyT  = w + offKey;
  float* S     = w + offS;
  float* candK = w + offCK;
  int*   candI = (int*)(w + offCI);
  float* dots  = w + offDots;

  k_key<<<dim3((N + KROWS - 1) / KROWS), dim3(256), 0, stream>>>(XN, C, keyT, N);
  k_gramsolve<<<dim3(1), dim3(1024), 0, stream>>>(C, W, S, out, bs);
  k_pred<<<dim3(bs * SPLIT / 256), dim3(256), 0, stream>>>(Xb, C, W, bv, S, out, bs);
  k_topk<<<dim3(NBLK, NC), dim3(256), 0, stream>>>(keyT, candK, candI, N);
  k_final<<<dim3(NC), dim3(256), 0, stream>>>(candK, candI, XN, C, dots);
  k_scal<<<dim3(1), dim3(64), 0, stream>>>(dots, out, bs);
}